// Round 7
// baseline (134.648 us; speedup 1.0000x reference)
//
#include <hip/hip_runtime.h>
#include <stdint.h>

// Tropical (max-plus) matmul: out[n,m] = max_k(|x[n,k]| + |w[m,k]|)
// N=1024, K=256, M=1024, fp32.
//
// Round 7: two-pass. Prep writes |x| (1 MB) and |w| transposed to quad
// layout wq[kq][m] (v4f = k 4kq..4kq+3 of column m) into d_ws. Main kernel
// is pure streaming VALU: coalesced w loads (lane=m), uniform x loads,
// no abs / LDS / barriers / atomics in the hot loop.
// Inner loop: per 4-k group = 1 w-dwordx4 + 4 x-dwordx4 + 8 v_pk_add_f32
// + 8 v_max3_f32 (1 VALU inst per k per output). Double-buffered groups.
// Grid 1024 blocks x 256 thr = 4 blocks/CU = 4 waves/SIMD, VGPR ~95.

typedef float v2f __attribute__((ext_vector_type(2)));
typedef float v4f __attribute__((ext_vector_type(4)));

constexpr int K  = 256;
constexpr int M  = 1024;
constexpr int KQ = K / 4;   // 64 k-quads

static __device__ inline v4f abs4(v4f t) {
    return (v4f){fabsf(t.x), fabsf(t.y), fabsf(t.z), fabsf(t.w)};
}

// ---- Pass 1: blocks 0..255  -> xa = |x|           (coalesced r/w)
//              blocks 256..511 -> wq[kq][m] = |w^T|  (coalesced read, 16B
//              scattered writes; only 1 MB total, L2 absorbs)
__global__ void __launch_bounds__(256)
prep_kernel(const float* __restrict__ xg, const float* __restrict__ wg,
            float* __restrict__ xa, float* __restrict__ wqf)
{
    const int b   = blockIdx.x;
    const int tid = threadIdx.x;
    if (b < 256) {
        const v4f* src = (const v4f*)xg;
        v4f* dst = (v4f*)xa;
        const int i = b * 256 + tid;        // 65536 v4f = 1024x256 floats
        dst[i] = abs4(src[i]);
    } else {
        const int b2   = b - 256;
        const int m    = b2 * 4 + (tid >> 6);   // 4 m-rows per block
        const int lane = tid & 63;              // kq = lane
        const v4f* wrow = (const v4f*)(wg + m * K);   // 64 v4f per row
        v4f* wq = (v4f*)wqf;
        v4f t = wrow[lane];                     // coalesced: wave = 1 KB row
        wq[lane * M + m] = abs4(t);             // [kq][m]
    }
}

// ---- Pass 2: main kernel. lane <-> m, 4 n-rows per wave.
__global__ void __launch_bounds__(256)
tropical_kernel(const float* __restrict__ xa, const float* __restrict__ wqf,
                float* __restrict__ outg)
{
    const v4f* wq = (const v4f*)wqf;   // [kq][m]
    const v4f* xq = (const v4f*)xa;    // [n][kq]

    const int tid  = threadIdx.x;
    const int lane = tid & 63;
    const int wv   = __builtin_amdgcn_readfirstlane(tid >> 6);  // 0..3

    const int bn = (int)(blockIdx.x >> 4) * 16;
    const int bm = (int)(blockIdx.x & 15) * 64;
    const int n0 = bn + 4 * wv;

    const v4f* wbase = wq + bm + lane;   // + kq*M     (coalesced per wave)
    const v4f* xbase = xq + n0 * KQ;     // + j*KQ + kq (uniform per wave)

    float acc[4] = {0.f, 0.f, 0.f, 0.f};   // sums >= 0: safe identity

    // Double-buffered groups of 2 k-quads (8 k).
    v4f wb[2][2], xb[2][4][2];
#pragma unroll
    for (int u = 0; u < 2; ++u) {
        wb[0][u] = wbase[u * M];
#pragma unroll
        for (int j = 0; j < 4; ++j) xb[0][j][u] = xbase[j * KQ + u];
    }

#pragma unroll
    for (int g = 0; g < KQ / 2; ++g) {
        const int cur = g & 1, nxt = cur ^ 1;
        if (g + 1 < KQ / 2) {
            const int kq = (g + 1) * 2;
#pragma unroll
            for (int u = 0; u < 2; ++u) {
                wb[nxt][u] = wbase[(kq + u) * M];
#pragma unroll
                for (int j = 0; j < 4; ++j)
                    xb[nxt][j][u] = xbase[j * KQ + kq + u];
            }
        }
#pragma unroll
        for (int u = 0; u < 2; ++u) {
            const v4f W = wb[cur][u];
#pragma unroll
            for (int j = 0; j < 4; ++j) {
                const v4f X = xb[cur][j][u];
                v2f s0 = (v2f){X.x, X.y} + (v2f){W.x, W.y};   // v_pk_add_f32
                acc[j] = fmaxf(acc[j], fmaxf(s0.x, s0.y));    // v_max3_f32
                v2f s1 = (v2f){X.z, X.w} + (v2f){W.z, W.w};
                acc[j] = fmaxf(acc[j], fmaxf(s1.x, s1.y));
            }
        }
    }

    // Coalesced stores: lane = m.
#pragma unroll
    for (int j = 0; j < 4; ++j)
        outg[(n0 + j) * M + bm + lane] = acc[j];
}

extern "C" void kernel_launch(void* const* d_in, const int* in_sizes, int n_in,
                              void* d_out, int out_size, void* d_ws, size_t ws_size,
                              hipStream_t stream)
{
    const float* x = (const float*)d_in[0];   // [1024, 256]
    const float* w = (const float*)d_in[1];   // [1024, 256]
    float* out = (float*)d_out;               // [1024, 1024]

    float* xa = (float*)d_ws;                 // 1 MB |x|
    float* wq = (float*)d_ws + (1 << 18);     // 1 MB |w^T| quad layout

    prep_kernel<<<dim3(512), dim3(256), 0, stream>>>(x, w, xa, wq);
    tropical_kernel<<<dim3(1024), dim3(256), 0, stream>>>(xa, wq, out);
}